// Round 1
// baseline (171.588 us; speedup 1.0000x reference)
//
#include <hip/hip_runtime.h>

// MorphologicalDilation: out[b,i,j,f] = max_{p in 0..8} (x[b, i+p/3, j+p%3, 0] + w[p, f])
// x: (16, 256, 256, 1) fp32, w: (1,1,1,9,32) fp32 -> out: (16, 254, 254, 32) fp32
// Write-BW bound: 132 MB out + 4 MB in => ~22 us floor at 6.3 TB/s.

#define BB 16
#define HH 256
#define WW 256
#define KHH 3
#define KWW 3
#define FF 32
#define HO (HH - KHH + 1)   // 254
#define WO (WW - KWW + 1)   // 254

__global__ __launch_bounds__(256) void
dilate_kernel(const float* __restrict__ x, const float* __restrict__ w,
              float* __restrict__ out) {
    // Thread layout: 8 lanes per pixel, each lane owns 4 consecutive filters (float4).
    // Consecutive tids -> consecutive 16B output chunks -> perfectly coalesced stores.
    const long long tid = (long long)blockIdx.x * blockDim.x + threadIdx.x;
    const int fq  = (int)(tid & 7);        // filter quad 0..7 -> filters fq*4..fq*4+3
    const long long pix = tid >> 3;        // linear pixel over (B, Ho, Wo)
    if (pix >= (long long)BB * HO * WO) return;

    const int j = (int)(pix % WO);
    const int t = (int)(pix / WO);
    const int i = t % HO;
    const int b = t / HO;

    // 9 patch values (broadcast across the 8 lanes of this pixel group)
    const float* xb = x + ((long long)b * HH + i) * WW + j;
    float xv[9];
#pragma unroll
    for (int di = 0; di < 3; ++di) {
#pragma unroll
        for (int dj = 0; dj < 3; ++dj) {
            xv[di * 3 + dj] = xb[di * WW + dj];
        }
    }

    // w layout: w[p*32 + f]; as float4: w4[p*8 + fq]
    const float4* __restrict__ w4 = (const float4*)w;

    float4 wv = w4[fq];               // p = 0
    float4 m;
    m.x = xv[0] + wv.x;
    m.y = xv[0] + wv.y;
    m.z = xv[0] + wv.z;
    m.w = xv[0] + wv.w;
#pragma unroll
    for (int p = 1; p < 9; ++p) {
        wv = w4[p * 8 + fq];
        m.x = fmaxf(m.x, xv[p] + wv.x);
        m.y = fmaxf(m.y, xv[p] + wv.y);
        m.z = fmaxf(m.z, xv[p] + wv.z);
        m.w = fmaxf(m.w, xv[p] + wv.w);
    }

    ((float4*)out)[pix * 8 + fq] = m;
}

extern "C" void kernel_launch(void* const* d_in, const int* in_sizes, int n_in,
                              void* d_out, int out_size, void* d_ws, size_t ws_size,
                              hipStream_t stream) {
    const float* x = (const float*)d_in[0];
    const float* w = (const float*)d_in[1];
    float* out = (float*)d_out;

    const long long total_threads = (long long)BB * HO * WO * 8;  // 8,258,048
    const int block = 256;
    const int grid = (int)((total_threads + block - 1) / block);  // 32,258

    dilate_kernel<<<grid, block, 0, stream>>>(x, w, out);
}

// Round 2
// 157.729 us; speedup vs baseline: 1.0879x; 1.0879x over previous
//
#include <hip/hip_runtime.h>

// MorphologicalDilation: out[b,i,j,f] = max_{p in 0..8} (x[b, i+p/3, j+p%3, 0] + w[p, f])
// x: (16, 256, 256, 1) fp32, w: (1,1,1,9,32) fp32 -> out: (16, 254, 254, 32) fp32
// Write-BW bound: 132 MB out => ~22 us floor at 6.3 TB/s achievable.
//
// Layout: 8 lanes per pixel (each lane owns a float4 of 4 filters), 2 adjacent
// pixels (along j) per thread. 3D grid carries (j-block, i, b) -> no divides.

#define BB 16
#define HH 256
#define WW 256
#define FF 32
#define HO 254
#define WO 254

__global__ __launch_bounds__(256) void
dilate_kernel(const float* __restrict__ x, const float* __restrict__ w,
              float* __restrict__ out) {
    const int fq = threadIdx.x & 7;       // filter quad: filters fq*4..fq*4+3
    const int pp = threadIdx.x >> 3;      // pixel pair within block: 0..31
    const int j0 = (blockIdx.x << 6) + (pp << 1);  // 64 pixels per block along j
    if (j0 >= WO) return;                 // WO even, j0 even => j0+1 < WO too
    const int i = blockIdx.y;
    const int b = blockIdx.z;

    // 9 w fragments into registers (reused for both pixels); imm-offset loads.
    const float4* __restrict__ w4 = (const float4*)w + fq;
    float4 wv[9];
#pragma unroll
    for (int p = 0; p < 9; ++p) wv[p] = w4[p * 8];

    // x window: rows i..i+2, cols j0..j0+3 (12 values, two float2 per row).
    const float* xb = x + ((b * HH + i) * WW + j0);
    float xv[3][4];
#pragma unroll
    for (int r = 0; r < 3; ++r) {
        const float2 lo = *(const float2*)(xb + r * WW);
        const float2 hi = *(const float2*)(xb + r * WW + 2);
        xv[r][0] = lo.x; xv[r][1] = lo.y; xv[r][2] = hi.x; xv[r][3] = hi.y;
    }

    float4 m0, m1;
#pragma unroll
    for (int r = 0; r < 3; ++r) {
#pragma unroll
        for (int c = 0; c < 3; ++c) {
            const int p = r * 3 + c;
            const float a0 = xv[r][c];
            const float a1 = xv[r][c + 1];
            if (p == 0) {
                m0.x = a0 + wv[0].x; m0.y = a0 + wv[0].y;
                m0.z = a0 + wv[0].z; m0.w = a0 + wv[0].w;
                m1.x = a1 + wv[0].x; m1.y = a1 + wv[0].y;
                m1.z = a1 + wv[0].z; m1.w = a1 + wv[0].w;
            } else {
                m0.x = fmaxf(m0.x, a0 + wv[p].x);
                m0.y = fmaxf(m0.y, a0 + wv[p].y);
                m0.z = fmaxf(m0.z, a0 + wv[p].z);
                m0.w = fmaxf(m0.w, a0 + wv[p].w);
                m1.x = fmaxf(m1.x, a1 + wv[p].x);
                m1.y = fmaxf(m1.y, a1 + wv[p].y);
                m1.z = fmaxf(m1.z, a1 + wv[p].z);
                m1.w = fmaxf(m1.w, a1 + wv[p].w);
            }
        }
    }

    // Store: per instruction, lanes fq=0..7 write one contiguous 128B chunk
    // per pixel-pair group (chunks 256B apart across pp) -> clean coalescing.
    float4* o4 = (float4*)out + (((b * HO + i) * WO + j0) * 8 + fq);
    o4[0] = m0;   // pixel j0
    o4[8] = m1;   // pixel j0+1
}

extern "C" void kernel_launch(void* const* d_in, const int* in_sizes, int n_in,
                              void* d_out, int out_size, void* d_ws, size_t ws_size,
                              hipStream_t stream) {
    const float* x = (const float*)d_in[0];
    const float* w = (const float*)d_in[1];
    float* out = (float*)d_out;

    dim3 grid((WO + 63) / 64, HO, BB);   // (4, 254, 16)
    dilate_kernel<<<grid, 256, 0, stream>>>(x, w, out);
}

// Round 3
// 152.336 us; speedup vs baseline: 1.1264x; 1.0354x over previous
//
#include <hip/hip_runtime.h>

// MorphologicalDilation: out[b,i,j,f] = max_{p in 0..8} (x[b, i+p/3, j+p%3, 0] + w[p, f])
// x: (16, 256, 256, 1) fp32, w: (1,1,1,9,32) fp32 -> out: (16, 254, 254, 32) fp32
// Write-BW bound: 132 MB out => ~21 us floor at 6.3 TB/s achievable.
//
// Layout: 8 lanes per pixel (each lane owns a float4 of 4 filters), 4 adjacent
// pixels (along j) per thread. 3D grid carries (j-block, i, b) -> no divides.
// Max-reduction written as max3-friendly trees (4 x v_max3_f32 per component).

#define BB 16
#define HH 256
#define WW 256
#define FF 32
#define HO 254
#define WO 254

__device__ __forceinline__ float4 f4add(float a, float4 w) {
    return make_float4(a + w.x, a + w.y, a + w.z, a + w.w);
}
__device__ __forceinline__ float4 f4max(float4 a, float4 b) {
    return make_float4(fmaxf(a.x, b.x), fmaxf(a.y, b.y),
                       fmaxf(a.z, b.z), fmaxf(a.w, b.w));
}

__global__ __launch_bounds__(256) void
dilate_kernel(const float* __restrict__ x, const float* __restrict__ w,
              float* __restrict__ out) {
    const int fq = threadIdx.x & 7;        // filter quad: filters fq*4..fq*4+3
    const int pp = threadIdx.x >> 3;       // pixel group within block: 0..31
    const int j0 = (blockIdx.x << 7) + (pp << 2);  // 128 pixels per block along j
    const int i = blockIdx.y;
    const int b = blockIdx.z;

    // 9 w fragments into registers (reused for all 4 pixels).
    const float4* __restrict__ w4 = (const float4*)w + fq;
    float4 wv[9];
#pragma unroll
    for (int p = 0; p < 9; ++p) wv[p] = w4[p * 8];

    // x window: rows i..i+2, cols j0..j0+5 (float4 + guarded float2 per row).
    const float* xb = x + ((b * HH + i) * WW + j0);
    const bool tail_ok = (j0 + 5 < WW);    // false only for the last pixel group
    float xv[3][6];
#pragma unroll
    for (int r = 0; r < 3; ++r) {
        const float4 lo = *(const float4*)(xb + r * WW);
        xv[r][0] = lo.x; xv[r][1] = lo.y; xv[r][2] = lo.z; xv[r][3] = lo.w;
        if (tail_ok) {
            const float2 hi = *(const float2*)(xb + r * WW + 4);
            xv[r][4] = hi.x; xv[r][5] = hi.y;
        } else {
            xv[r][4] = 0.f; xv[r][5] = 0.f;  // feeds only out-of-range pixels
        }
    }

    float4* o4 = (float4*)out + (((b * HO + i) * WO + j0) * 8 + fq);

#pragma unroll
    for (int k = 0; k < 4; ++k) {
        // 9 sums, then max3-shaped tree: max3(s012), max3(s345), max3(s678), max3(t,t,t)
        float4 t0, t1, t2;
#pragma unroll
        for (int r = 0; r < 3; ++r) {
            float4 s0 = f4add(xv[r][k + 0], wv[r * 3 + 0]);
            float4 s1 = f4add(xv[r][k + 1], wv[r * 3 + 1]);
            float4 s2 = f4add(xv[r][k + 2], wv[r * 3 + 2]);
            float4 t  = f4max(f4max(s0, s1), s2);   // -> v_max3_f32
            if (r == 0) t0 = t; else if (r == 1) t1 = t; else t2 = t;
        }
        const float4 m = f4max(f4max(t0, t1), t2);  // -> v_max3_f32

        if (j0 + k < WO) o4[k * 8] = m;
    }
}

extern "C" void kernel_launch(void* const* d_in, const int* in_sizes, int n_in,
                              void* d_out, int out_size, void* d_ws, size_t ws_size,
                              hipStream_t stream) {
    const float* x = (const float*)d_in[0];
    const float* w = (const float*)d_in[1];
    float* out = (float*)d_out;

    dim3 grid((WO + 127) / 128, HO, BB);   // (2, 254, 16)
    dilate_kernel<<<grid, 256, 0, stream>>>(x, w, out);
}